// Round 8
// baseline (365.221 us; speedup 1.0000x reference)
//
#include <hip/hip_runtime.h>
#include <cstddef>
#include <cstdint>

// Problem constants (fixed by the reference)
#define NN 50000      // nodes
#define EE 800000     // edges (before self loops)
#define FIN 128
#define D1 256        // HEADS*HID
#define HID 64
#define HEADS 4
#define NG 512
#define FOUT 64
#define NEG_SLOPE 0.2f
#define CAP 96        // slots per node; deg ~ Poisson(16), P(deg>96) ~ 1e-40

// R1-R6 arc (channel-sliced aggregation) refuted: L2 residency real
// (FETCH 216->59 MB) but 8x metadata redundancy floors it at ~83 us vs
// R0's 65. R7 reverted to R0 structure (u16 slots kept), reproduced
// baseline counters exactly. R8: widen the gather — f16x8/lane, wave
// covers 2 edges/instruction, halving iterations and doubling bytes in
// flight; merge halves with one shfl_xor(32) at the end.

typedef _Float16 f16x8 __attribute__((ext_vector_type(8)));
typedef _Float16 f16x4 __attribute__((ext_vector_type(4)));
typedef float f32x4 __attribute__((ext_vector_type(4)));

__device__ __forceinline__ float leaky(float x) { return x > 0.f ? x : NEG_SLOPE * x; }

// ---------------------------------------------------------------------------
// Adjacency build, scan-free: fixed-capacity slot array (CAP per node), u16.
// ---------------------------------------------------------------------------
__global__ void k_scatter_direct(const int* __restrict__ ei, int* __restrict__ cnt,
                                 unsigned short* __restrict__ slot) {
    int i = blockIdx.x * 256 + threadIdx.x;
    if (i < EE) {
        int s = ei[i], d = ei[EE + i];
        int p = atomicAdd(&cnt[d], 1);
        if (p < CAP)
            __builtin_nontemporal_store((unsigned short)s, &slot[(size_t)d * CAP + p]);
    }
}

// ---------------------------------------------------------------------------
// Weight transposes: W[K][256] fp32 -> Wt[256][K] fp16, both layers, 1 kernel
// ---------------------------------------------------------------------------
__global__ void k_cvt_w(const float* __restrict__ W1, const float* __restrict__ W2,
                        _Float16* __restrict__ w1t, _Float16* __restrict__ w2t) {
    int idx = blockIdx.x * 256 + threadIdx.x;
    if (idx < 256 * FIN) {
        int n = idx / FIN, k = idx - n * FIN;
        w1t[idx] = (_Float16)W1[(size_t)k * 256 + n];
    } else if (idx < 256 * FIN + 256 * D1) {
        int j = idx - 256 * FIN;
        int n = j >> 8, k = j & 255;
        w2t[j] = (_Float16)W2[(size_t)k * 256 + n];
    }
}

// ---------------------------------------------------------------------------
// MFMA fp16 GEMM (NT) with FUSED attention logits epilogue.
// C[M,256] = A[M,K] * Bt[256,K]^T, fp32 acc, fp16 out (row-major).
// BM=BN=128, BK=64; 4 waves 2x2; swapped-operand MFMA. Each wave's 64-ch
// slice == one head (head = 2*by + wn); a_s/a_d computed wave-locally.
// A is fp32 (layer 1, x) or fp16 (layer 2) via template.
// ---------------------------------------------------------------------------
#define BM 128
#define BN 128
#define BK 64
#define LDK (BK + 4)

template <int K, typename AT>
__global__ __launch_bounds__(256) void k_gemm(const AT* __restrict__ A,
                                              const _Float16* __restrict__ Bt,
                                              _Float16* __restrict__ C,
                                              const float* __restrict__ att_s,
                                              const float* __restrict__ att_d,
                                              float* __restrict__ a_s,
                                              float* __restrict__ a_d) {
    __shared__ _Float16 As[BM][LDK];
    __shared__ _Float16 Bs[BN][LDK];
    const int tid = threadIdx.x;
    const int lane = tid & 63;
    const int wave = tid >> 6;            // 0..3
    const int wm = wave & 1, wn = wave >> 1;
    const int m0 = blockIdx.x * BM;
    const int n0 = blockIdx.y * BN;
    const int row_m = lane & 15, quad = lane >> 4;

    f32x4 acc[4][4];
#pragma unroll
    for (int mi = 0; mi < 4; ++mi)
#pragma unroll
        for (int ni = 0; ni < 4; ++ni)
#pragma unroll
            for (int r = 0; r < 4; ++r) acc[mi][ni][r] = 0.f;

    const int c8 = (tid & 7) * 8;          // f16 column offset within row
    const int rr = tid >> 3;               // 0..31

    for (int k0 = 0; k0 < K; k0 += BK) {
#pragma unroll
        for (int p = 0; p < 4; ++p) {
            int r = p * 32 + rr;
            int gr = m0 + r; gr = gr < NN ? gr : NN - 1;
            f16x8 o;
            if constexpr (sizeof(AT) == 4) {
                const float4 v0 = *(const float4*)((const float*)A + (size_t)gr * K + k0 + c8);
                const float4 v1 = *(const float4*)((const float*)A + (size_t)gr * K + k0 + c8 + 4);
                o[0] = (_Float16)v0.x; o[1] = (_Float16)v0.y;
                o[2] = (_Float16)v0.z; o[3] = (_Float16)v0.w;
                o[4] = (_Float16)v1.x; o[5] = (_Float16)v1.y;
                o[6] = (_Float16)v1.z; o[7] = (_Float16)v1.w;
            } else {
                o = *(const f16x8*)((const _Float16*)A + (size_t)gr * K + k0 + c8);
            }
            *(f16x8*)(&As[r][c8]) = o;
        }
#pragma unroll
        for (int p = 0; p < 4; ++p) {
            int r = p * 32 + rr;
            f16x8 v = *(const f16x8*)(Bt + (size_t)(n0 + r) * K + k0 + c8);
            *(f16x8*)(&Bs[r][c8]) = v;
        }
        __syncthreads();
#pragma unroll
        for (int kc = 0; kc < BK; kc += 32) {
            f16x8 af[4], bf[4];
#pragma unroll
            for (int mi = 0; mi < 4; ++mi)
                af[mi] = *(const f16x8*)(&As[wm * 64 + mi * 16 + row_m][kc + quad * 8]);
#pragma unroll
            for (int ni = 0; ni < 4; ++ni)
                bf[ni] = *(const f16x8*)(&Bs[wn * 64 + ni * 16 + row_m][kc + quad * 8]);
            // swapped operands: D holds C^T fragment
#pragma unroll
            for (int mi = 0; mi < 4; ++mi)
#pragma unroll
                for (int ni = 0; ni < 4; ++ni)
                    acc[mi][ni] = __builtin_amdgcn_mfma_f32_16x16x32_f16(
                        bf[ni], af[mi], acc[mi][ni], 0, 0, 0);
        }
        __syncthreads();
    }
    // store C (row-major): value(lane, reg) of acc[mi][ni] =
    //   C[m0+wm*64+mi*16+row_m][n0+wn*64+ni*16+quad*4+reg]
#pragma unroll
    for (int mi = 0; mi < 4; ++mi) {
        int m = m0 + wm * 64 + mi * 16 + row_m;
        if (m < NN) {
#pragma unroll
            for (int ni = 0; ni < 4; ++ni) {
                f16x4 o;
                o[0] = (_Float16)acc[mi][ni][0];
                o[1] = (_Float16)acc[mi][ni][1];
                o[2] = (_Float16)acc[mi][ni][2];
                o[3] = (_Float16)acc[mi][ni][3];
                *(f16x4*)(C + (size_t)m * D1 + n0 + wn * 64 + ni * 16 + quad * 4) = o;
            }
        }
    }
    // fused logits: this wave's 64 channels == head (2*by + wn); local channel
    // of acc[mi][ni][r] is ni*16 + quad*4 + r.
    const int head = blockIdx.y * 2 + wn;
    const float* attsv = att_s + head * HID;
    const float* attdv = att_d + head * HID;
    float avs[4][4], avd[4][4];
#pragma unroll
    for (int ni = 0; ni < 4; ++ni)
#pragma unroll
        for (int r = 0; r < 4; ++r) {
            avs[ni][r] = attsv[ni * 16 + quad * 4 + r];
            avd[ni][r] = attdv[ni * 16 + quad * 4 + r];
        }
#pragma unroll
    for (int mi = 0; mi < 4; ++mi) {
        float ps = 0.f, pd = 0.f;
#pragma unroll
        for (int ni = 0; ni < 4; ++ni)
#pragma unroll
            for (int r = 0; r < 4; ++r) {
                ps += acc[mi][ni][r] * avs[ni][r];
                pd += acc[mi][ni][r] * avd[ni][r];
            }
        ps += __shfl_xor(ps, 16); ps += __shfl_xor(ps, 32);
        pd += __shfl_xor(pd, 16); pd += __shfl_xor(pd, 32);
        int m = m0 + wm * 64 + mi * 16 + row_m;
        if (quad == 0 && m < NN) {
            a_s[m * 4 + head] = ps;   // node-major [NN][4]
            a_d[m * 4 + head] = pd;
        }
    }
}

// ---------------------------------------------------------------------------
// GAT softmax + aggregation, R8: one wave per dst node, 2 EDGES PER
// ITERATION. Lane half hi = tid>>5 owns edge 2p+hi; each lane holds 8
// channels (f16x8, 16 B) -> one wave-load fetches 1 KB (2 full rows).
// Iterations halve vs R0; bytes in flight double; per-edge loop overhead
// halves. Self-loop seeded in low half only; halves merged with one
// shfl_xor(32) pass at the end. Odd-degree pad: s=n, w=0 (L1-hot, safe).
// Phase 1 (unchanged): lanes batch-compute exp weights into LDS.
// ---------------------------------------------------------------------------
__global__ __launch_bounds__(64) void k_aggregate(
    const _Float16* __restrict__ h, const float* __restrict__ a_s,
    const float* __restrict__ a_d, const int* __restrict__ cnt,
    const unsigned short* __restrict__ slot, const float* __restrict__ bias,
    _Float16* __restrict__ out, int apply_elu) {
    const int n = blockIdx.x;
    const int tid = threadIdx.x;              // 0..63
    const int hi = tid >> 5;                  // edge-of-pair index
    const int lane32 = tid & 31;
    const int myhead = lane32 >> 3;           // 64 ch/head, 8 ch/lane
    const int c8 = lane32 * 8;                // channel base 0..248
    const int start = n * CAP;
    const int deg = cnt[n];
    const int len = deg < CAP ? deg : CAP;

    __shared__ float s_w[64][4];

    const float4 ad = *(const float4*)(a_d + (size_t)n * 4);
    const float4 asn = *(const float4*)(a_s + (size_t)n * 4);
    const float w0 = __expf(leaky(asn.x + ad.x));
    const float w1 = __expf(leaky(asn.y + ad.y));
    const float w2 = __expf(leaky(asn.z + ad.z));
    const float w3 = __expf(leaky(asn.w + ad.w));
    const float wself = (myhead == 0) ? w0 : (myhead == 1) ? w1 : (myhead == 2) ? w2 : w3;

    // self-loop seed in the LOW half only (merge would double-count otherwise)
    const f16x8 hn = *(const f16x8*)(h + ((size_t)n << 8) + c8);
    const float seed = hi ? 0.f : wself;
    float l = seed;
    float acc[8];
#pragma unroll
    for (int k = 0; k < 8; ++k) acc[k] = seed * (float)hn[k];

    for (int base = 0; base < len; base += 64) {
        const int blen = min(64, len - base);
        if (tid < blen) {
            const int s = (int)slot[start + base + tid];
            const float4 as = *(const float4*)(a_s + (size_t)s * 4);
            s_w[tid][0] = __expf(leaky(as.x + ad.x));
            s_w[tid][1] = __expf(leaky(as.y + ad.y));
            s_w[tid][2] = __expf(leaky(as.z + ad.z));
            s_w[tid][3] = __expf(leaky(as.w + ad.w));
        }
        __syncthreads();
        const int npair = (blen + 1) >> 1;
#pragma unroll 4
        for (int p = 0; p < npair; ++p) {
            const int j = 2 * p + hi;
            const bool act = j < blen;
            const int s = act ? (int)slot[start + base + j] : n;
            const float w = act ? s_w[j][myhead] : 0.f;
            const f16x8 hv = *(const f16x8*)(h + ((size_t)s << 8) + c8);
            l += w;
#pragma unroll
            for (int k = 0; k < 8; ++k) acc[k] += w * (float)hv[k];
        }
        __syncthreads();
    }
    // merge the two edge halves (channels identical across halves)
    l += __shfl_xor(l, 32);
#pragma unroll
    for (int k = 0; k < 8; ++k) acc[k] += __shfl_xor(acc[k], 32);

    const float inv = 1.f / l;
    if (hi == 0) {
        const float4 b0 = *(const float4*)(bias + c8);
        const float4 b1 = *(const float4*)(bias + c8 + 4);
        float v[8];
        v[0] = acc[0] * inv + b0.x; v[1] = acc[1] * inv + b0.y;
        v[2] = acc[2] * inv + b0.z; v[3] = acc[3] * inv + b0.w;
        v[4] = acc[4] * inv + b1.x; v[5] = acc[5] * inv + b1.y;
        v[6] = acc[6] * inv + b1.z; v[7] = acc[7] * inv + b1.w;
        if (apply_elu) {
#pragma unroll
            for (int k = 0; k < 8; ++k)
                v[k] = v[k] > 0.f ? v[k] : __expf(v[k]) - 1.f;  // f16 out: err ~1e-7
        }
        f16x8 o;
#pragma unroll
        for (int k = 0; k < 8; ++k) o[k] = (_Float16)v[k];
        *(f16x8*)(out + (size_t)n * D1 + c8) = o;
    }
}

// ---------------------------------------------------------------------------
// Fused global mean pool + final FC: one 256-thr block per graph.
// batch is sorted -> binary search node range; channel-per-thread sum;
// then threads 0..63 compute the FC row.
// ---------------------------------------------------------------------------
__global__ __launch_bounds__(256) void k_pool_fc(const _Float16* __restrict__ h,
                                                 const int* __restrict__ batch,
                                                 const float* __restrict__ fc_w,
                                                 const float* __restrict__ fc_b,
                                                 float* __restrict__ out) {
    __shared__ float row[D1];
    int g = blockIdx.x, c = threadIdx.x;
    int lo = 0, hi = NN;
    while (lo < hi) { int mid = (lo + hi) >> 1; if (batch[mid] < g) lo = mid + 1; else hi = mid; }
    int start = lo;
    hi = NN;
    while (lo < hi) { int mid = (lo + hi) >> 1; if (batch[mid] < g + 1) lo = mid + 1; else hi = mid; }
    int end = lo;

    float acc = 0.f;
    for (int n = start; n < end; ++n) acc += (float)h[(size_t)n * D1 + c];
    float inv = 1.f / fmaxf((float)(end - start), 1.f);
    row[c] = acc * inv;
    __syncthreads();
    if (c < FOUT) {
        float o = 0.f;
#pragma unroll 4
        for (int k = 0; k < D1; ++k) o += row[k] * fc_w[k * FOUT + c];
        out[(size_t)g * FOUT + c] = o + fc_b[c];
    }
}

// ---------------------------------------------------------------------------
extern "C" void kernel_launch(void* const* d_in, const int* in_sizes, int n_in,
                              void* d_out, int out_size, void* d_ws, size_t ws_size,
                              hipStream_t stream) {
    const float* x        = (const float*)d_in[0];
    const int*   ei       = (const int*)d_in[1];
    const int*   batch    = (const int*)d_in[2];
    const float* W1       = (const float*)d_in[3];
    const float* att_src1 = (const float*)d_in[4];
    const float* att_dst1 = (const float*)d_in[5];
    const float* b1       = (const float*)d_in[6];
    const float* W2       = (const float*)d_in[7];
    const float* att_src2 = (const float*)d_in[8];
    const float* att_dst2 = (const float*)d_in[9];
    const float* b2       = (const float*)d_in[10];
    const float* fc_w     = (const float*)d_in[11];
    const float* fc_b     = (const float*)d_in[12];
    float* out = (float*)d_out;

    // workspace carve-up (~55 MB)
    _Float16* h_pre  = (_Float16*)d_ws;                       // NN*D1 f16
    _Float16* h_act  = h_pre + (size_t)NN * D1;               // NN*D1 f16
    _Float16* w1t    = h_act + (size_t)NN * D1;               // 256*128
    _Float16* w2t    = w1t + 256 * FIN;                       // 256*256
    float* a_s       = (float*)(w2t + 256 * D1);              // [NN][4] node-major
    float* a_d       = a_s + (size_t)NN * 4;
    int*   cnt       = (int*)(a_d + (size_t)NN * 4);          // NN ints
    unsigned short* slot16 = (unsigned short*)(cnt + NN);     // NN*CAP u16 (9.6 MB)

    const int nblk_edges = (EE + 255) / 256;

    // ---- adjacency build (memset + single scatter; scan-free) ----
    hipMemsetAsync(cnt, 0, NN * sizeof(int), stream);
    k_scatter_direct<<<nblk_edges, 256, 0, stream>>>(ei, cnt, slot16);

    // ---- weight transposes (1 dispatch) ----
    k_cvt_w<<<(256 * (FIN + D1) + 255) / 256, 256, 0, stream>>>(W1, W2, w1t, w2t);

    dim3 ggrid((NN + BM - 1) / BM, D1 / BN);

    // ---- layer 1 (GEMM + fused logits, aggregate) ----
    k_gemm<FIN, float><<<ggrid, 256, 0, stream>>>(x, w1t, h_pre,
                                                  att_src1, att_dst1, a_s, a_d);
    k_aggregate<<<NN, 64, 0, stream>>>(h_pre, a_s, a_d, cnt, slot16, b1, h_act, 1);

    // ---- layer 2 ----
    k_gemm<D1, _Float16><<<ggrid, 256, 0, stream>>>(h_act, w2t, h_pre,
                                                    att_src2, att_dst2, a_s, a_d);
    k_aggregate<<<NN, 64, 0, stream>>>(h_pre, a_s, a_d, cnt, slot16, b2, h_act, 1);

    // ---- fused pool + fc ----
    k_pool_fc<<<NG, 256, 0, stream>>>(h_act, batch, fc_w, fc_b, out);
}

// Round 9
// 349.401 us; speedup vs baseline: 1.0453x; 1.0453x over previous
//
#include <hip/hip_runtime.h>
#include <cstddef>
#include <cstdint>

// Problem constants (fixed by the reference)
#define NN 50000      // nodes
#define EE 800000     // edges (before self loops)
#define FIN 128
#define D1 256        // HEADS*HID
#define HID 64
#define HEADS 4
#define NG 512
#define FOUT 64
#define NEG_SLOPE 0.2f
#define CAP 96        // slots per node; deg ~ Poisson(16), P(deg>96) ~ 1e-40

// Aggregate history: R1-R6 channel-sliced arc refuted (L2 residency real,
// FETCH 216->59 MB, but 8x metadata redundancy floors at ~83 us). R0/R7
// row-major wave-uniform form = 65.4 us @ 3.74 TB/s. R8 (2-edge f16x8)
// = 66.4 @ 3.77 -> rate invariant across 3 structures => pattern-bound
// memory wall (random 512-B bursts, 8-XCD refetch). Aggregate is at its
// structural roofline; R9 attacks the non-aggregate tail (scatter, pool).

typedef _Float16 f16x8 __attribute__((ext_vector_type(8)));
typedef _Float16 f16x4 __attribute__((ext_vector_type(4)));
typedef float f32x4 __attribute__((ext_vector_type(4)));

__device__ __forceinline__ float leaky(float x) { return x > 0.f ? x : NEG_SLOPE * x; }

// ---------------------------------------------------------------------------
// Adjacency build, scan-free: fixed-capacity slot array (CAP per node), u16.
// R9: 2 edges/thread, int2 loads (8 B/lane coalesced), half the waves.
// EE is even -> no odd tail.
// ---------------------------------------------------------------------------
__global__ void k_scatter_direct(const int* __restrict__ ei, int* __restrict__ cnt,
                                 unsigned short* __restrict__ slot) {
    int i = (blockIdx.x * 256 + threadIdx.x) * 2;
    if (i < EE) {
        const int2 s2 = *(const int2*)(ei + i);
        const int2 d2 = *(const int2*)(ei + EE + i);
        int p0 = atomicAdd(&cnt[d2.x], 1);
        if (p0 < CAP)
            __builtin_nontemporal_store((unsigned short)s2.x,
                                        &slot[(size_t)d2.x * CAP + p0]);
        int p1 = atomicAdd(&cnt[d2.y], 1);
        if (p1 < CAP)
            __builtin_nontemporal_store((unsigned short)s2.y,
                                        &slot[(size_t)d2.y * CAP + p1]);
    }
}

// ---------------------------------------------------------------------------
// Weight transposes: W[K][256] fp32 -> Wt[256][K] fp16, both layers, 1 kernel
// ---------------------------------------------------------------------------
__global__ void k_cvt_w(const float* __restrict__ W1, const float* __restrict__ W2,
                        _Float16* __restrict__ w1t, _Float16* __restrict__ w2t) {
    int idx = blockIdx.x * 256 + threadIdx.x;
    if (idx < 256 * FIN) {
        int n = idx / FIN, k = idx - n * FIN;
        w1t[idx] = (_Float16)W1[(size_t)k * 256 + n];
    } else if (idx < 256 * FIN + 256 * D1) {
        int j = idx - 256 * FIN;
        int n = j >> 8, k = j & 255;
        w2t[j] = (_Float16)W2[(size_t)k * 256 + n];
    }
}

// ---------------------------------------------------------------------------
// MFMA fp16 GEMM (NT) with FUSED attention logits epilogue.
// C[M,256] = A[M,K] * Bt[256,K]^T, fp32 acc, fp16 out (row-major).
// BM=BN=128, BK=64; 4 waves 2x2; swapped-operand MFMA. Each wave's 64-ch
// slice == one head (head = 2*by + wn); a_s/a_d computed wave-locally.
// A is fp32 (layer 1, x) or fp16 (layer 2) via template.
// SQ_LDS_BANK_CONFLICT measured 0 -> LDS pad +4 is conflict-free as is.
// ---------------------------------------------------------------------------
#define BM 128
#define BN 128
#define BK 64
#define LDK (BK + 4)

template <int K, typename AT>
__global__ __launch_bounds__(256) void k_gemm(const AT* __restrict__ A,
                                              const _Float16* __restrict__ Bt,
                                              _Float16* __restrict__ C,
                                              const float* __restrict__ att_s,
                                              const float* __restrict__ att_d,
                                              float* __restrict__ a_s,
                                              float* __restrict__ a_d) {
    __shared__ _Float16 As[BM][LDK];
    __shared__ _Float16 Bs[BN][LDK];
    const int tid = threadIdx.x;
    const int lane = tid & 63;
    const int wave = tid >> 6;            // 0..3
    const int wm = wave & 1, wn = wave >> 1;
    const int m0 = blockIdx.x * BM;
    const int n0 = blockIdx.y * BN;
    const int row_m = lane & 15, quad = lane >> 4;

    f32x4 acc[4][4];
#pragma unroll
    for (int mi = 0; mi < 4; ++mi)
#pragma unroll
        for (int ni = 0; ni < 4; ++ni)
#pragma unroll
            for (int r = 0; r < 4; ++r) acc[mi][ni][r] = 0.f;

    const int c8 = (tid & 7) * 8;          // f16 column offset within row
    const int rr = tid >> 3;               // 0..31

    for (int k0 = 0; k0 < K; k0 += BK) {
#pragma unroll
        for (int p = 0; p < 4; ++p) {
            int r = p * 32 + rr;
            int gr = m0 + r; gr = gr < NN ? gr : NN - 1;
            f16x8 o;
            if constexpr (sizeof(AT) == 4) {
                const float4 v0 = *(const float4*)((const float*)A + (size_t)gr * K + k0 + c8);
                const float4 v1 = *(const float4*)((const float*)A + (size_t)gr * K + k0 + c8 + 4);
                o[0] = (_Float16)v0.x; o[1] = (_Float16)v0.y;
                o[2] = (_Float16)v0.z; o[3] = (_Float16)v0.w;
                o[4] = (_Float16)v1.x; o[5] = (_Float16)v1.y;
                o[6] = (_Float16)v1.z; o[7] = (_Float16)v1.w;
            } else {
                o = *(const f16x8*)((const _Float16*)A + (size_t)gr * K + k0 + c8);
            }
            *(f16x8*)(&As[r][c8]) = o;
        }
#pragma unroll
        for (int p = 0; p < 4; ++p) {
            int r = p * 32 + rr;
            f16x8 v = *(const f16x8*)(Bt + (size_t)(n0 + r) * K + k0 + c8);
            *(f16x8*)(&Bs[r][c8]) = v;
        }
        __syncthreads();
#pragma unroll
        for (int kc = 0; kc < BK; kc += 32) {
            f16x8 af[4], bf[4];
#pragma unroll
            for (int mi = 0; mi < 4; ++mi)
                af[mi] = *(const f16x8*)(&As[wm * 64 + mi * 16 + row_m][kc + quad * 8]);
#pragma unroll
            for (int ni = 0; ni < 4; ++ni)
                bf[ni] = *(const f16x8*)(&Bs[wn * 64 + ni * 16 + row_m][kc + quad * 8]);
            // swapped operands: D holds C^T fragment
#pragma unroll
            for (int mi = 0; mi < 4; ++mi)
#pragma unroll
                for (int ni = 0; ni < 4; ++ni)
                    acc[mi][ni] = __builtin_amdgcn_mfma_f32_16x16x32_f16(
                        bf[ni], af[mi], acc[mi][ni], 0, 0, 0);
        }
        __syncthreads();
    }
    // store C (row-major): value(lane, reg) of acc[mi][ni] =
    //   C[m0+wm*64+mi*16+row_m][n0+wn*64+ni*16+quad*4+reg]
#pragma unroll
    for (int mi = 0; mi < 4; ++mi) {
        int m = m0 + wm * 64 + mi * 16 + row_m;
        if (m < NN) {
#pragma unroll
            for (int ni = 0; ni < 4; ++ni) {
                f16x4 o;
                o[0] = (_Float16)acc[mi][ni][0];
                o[1] = (_Float16)acc[mi][ni][1];
                o[2] = (_Float16)acc[mi][ni][2];
                o[3] = (_Float16)acc[mi][ni][3];
                *(f16x4*)(C + (size_t)m * D1 + n0 + wn * 64 + ni * 16 + quad * 4) = o;
            }
        }
    }
    // fused logits: this wave's 64 channels == head (2*by + wn); local channel
    // of acc[mi][ni][r] is ni*16 + quad*4 + r.
    const int head = blockIdx.y * 2 + wn;
    const float* attsv = att_s + head * HID;
    const float* attdv = att_d + head * HID;
    float avs[4][4], avd[4][4];
#pragma unroll
    for (int ni = 0; ni < 4; ++ni)
#pragma unroll
        for (int r = 0; r < 4; ++r) {
            avs[ni][r] = attsv[ni * 16 + quad * 4 + r];
            avd[ni][r] = attdv[ni * 16 + quad * 4 + r];
        }
#pragma unroll
    for (int mi = 0; mi < 4; ++mi) {
        float ps = 0.f, pd = 0.f;
#pragma unroll
        for (int ni = 0; ni < 4; ++ni)
#pragma unroll
            for (int r = 0; r < 4; ++r) {
                ps += acc[mi][ni][r] * avs[ni][r];
                pd += acc[mi][ni][r] * avd[ni][r];
            }
        ps += __shfl_xor(ps, 16); ps += __shfl_xor(ps, 32);
        pd += __shfl_xor(pd, 16); pd += __shfl_xor(pd, 32);
        int m = m0 + wm * 64 + mi * 16 + row_m;
        if (quad == 0 && m < NN) {
            a_s[m * 4 + head] = ps;   // node-major [NN][4]
            a_d[m * 4 + head] = pd;
        }
    }
}

// ---------------------------------------------------------------------------
// GAT softmax + aggregation (R7-proven form, at its pattern roofline):
// one wave per dst node, 64-thr blocks. Self-loop folded in.
// Phase 1: lanes batch-compute exp weights into LDS. Phase 2: wave-uniform
// scalar loop — slot[j] uniform load, weight via LDS broadcast, f16x4 gather.
// ---------------------------------------------------------------------------
__global__ __launch_bounds__(64) void k_aggregate(
    const _Float16* __restrict__ h, const float* __restrict__ a_s,
    const float* __restrict__ a_d, const int* __restrict__ cnt,
    const unsigned short* __restrict__ slot, const float* __restrict__ bias,
    _Float16* __restrict__ out, int apply_elu) {
    const int n = blockIdx.x;
    const int tid = threadIdx.x;              // 0..63
    const int myhead = tid >> 4;
    const int c4 = tid * 4;
    const int start = n * CAP;
    const int deg = cnt[n];
    const int end = start + (deg < CAP ? deg : CAP);

    __shared__ float s_w[64][4];

    const float4 ad = *(const float4*)(a_d + (size_t)n * 4);

    // self-loop seed: w_self per head, acc = w_self * h[n]
    const float4 asn = *(const float4*)(a_s + (size_t)n * 4);
    float w0 = __expf(leaky(asn.x + ad.x));
    float w1 = __expf(leaky(asn.y + ad.y));
    float w2 = __expf(leaky(asn.z + ad.z));
    float w3 = __expf(leaky(asn.w + ad.w));
    const float wself = (myhead == 0) ? w0 : (myhead == 1) ? w1 : (myhead == 2) ? w2 : w3;
    const f16x4 hn = *(const f16x4*)(h + ((size_t)n << 8) + c4);
    float l = wself;
    float4 acc = make_float4(wself * (float)hn[0], wself * (float)hn[1],
                             wself * (float)hn[2], wself * (float)hn[3]);

    for (int base = start; base < end; base += 64) {
        const int len = min(64, end - base);
        if (tid < len) {
            const int s = (int)slot[base + tid];
            const float4 as = *(const float4*)(a_s + (size_t)s * 4);
            s_w[tid][0] = __expf(leaky(as.x + ad.x));
            s_w[tid][1] = __expf(leaky(as.y + ad.y));
            s_w[tid][2] = __expf(leaky(as.z + ad.z));
            s_w[tid][3] = __expf(leaky(as.w + ad.w));
        }
        __syncthreads();
#pragma unroll 4
        for (int jj = 0; jj < len; ++jj) {
            const int s = (int)slot[base + jj];         // wave-uniform
            const float w = s_w[jj][myhead];
            const f16x4 hv = *(const f16x4*)(h + ((size_t)s << 8) + c4);
            l += w;
            acc.x += w * (float)hv[0];
            acc.y += w * (float)hv[1];
            acc.z += w * (float)hv[2];
            acc.w += w * (float)hv[3];
        }
        __syncthreads();
    }
    const float inv = 1.f / l;
    const float4 bb = *(const float4*)(bias + c4);
    float vx = acc.x * inv + bb.x;
    float vy = acc.y * inv + bb.y;
    float vz = acc.z * inv + bb.z;
    float vw = acc.w * inv + bb.w;
    if (apply_elu) {
        vx = vx > 0.f ? vx : expm1f(vx);
        vy = vy > 0.f ? vy : expm1f(vy);
        vz = vz > 0.f ? vz : expm1f(vz);
        vw = vw > 0.f ? vw : expm1f(vw);
    }
    f16x4 o;
    o[0] = (_Float16)vx; o[1] = (_Float16)vy; o[2] = (_Float16)vz; o[3] = (_Float16)vw;
    *(f16x4*)(out + (size_t)n * D1 + c4) = o;
}

// ---------------------------------------------------------------------------
// Fused global mean pool + final FC: one 256-thr block per graph.
// R9: 4-warp vectorized sum — warp w owns node-stripe start+w, start+w+4, ...;
// lane reads f16x4 (512 B per wave-load = full row, 4x fewer load insts than
// the scalar-per-channel form). Stripes combined in LDS, then FC.
// ---------------------------------------------------------------------------
__global__ __launch_bounds__(256) void k_pool_fc(const _Float16* __restrict__ h,
                                                 const int* __restrict__ batch,
                                                 const float* __restrict__ fc_w,
                                                 const float* __restrict__ fc_b,
                                                 float* __restrict__ out) {
    __shared__ float srow[4][D1];
    __shared__ float row[D1];
    const int g = blockIdx.x, tid = threadIdx.x;
    const int w = tid >> 6, lane = tid & 63;
    const int c4 = lane * 4;

    int lo = 0, hi = NN;
    while (lo < hi) { int mid = (lo + hi) >> 1; if (batch[mid] < g) lo = mid + 1; else hi = mid; }
    int start = lo;
    hi = NN;
    while (lo < hi) { int mid = (lo + hi) >> 1; if (batch[mid] < g + 1) lo = mid + 1; else hi = mid; }
    int end = lo;

    float a0 = 0.f, a1 = 0.f, a2 = 0.f, a3 = 0.f;
    for (int n = start + w; n < end; n += 4) {
        const f16x4 v = *(const f16x4*)(h + (size_t)n * D1 + c4);
        a0 += (float)v[0]; a1 += (float)v[1];
        a2 += (float)v[2]; a3 += (float)v[3];
    }
    srow[w][c4 + 0] = a0; srow[w][c4 + 1] = a1;
    srow[w][c4 + 2] = a2; srow[w][c4 + 3] = a3;
    __syncthreads();
    const float inv = 1.f / fmaxf((float)(end - start), 1.f);
    row[tid] = (srow[0][tid] + srow[1][tid] + srow[2][tid] + srow[3][tid]) * inv;
    __syncthreads();
    if (tid < FOUT) {
        float o = 0.f;
#pragma unroll 4
        for (int k = 0; k < D1; ++k) o += row[k] * fc_w[k * FOUT + tid];
        out[(size_t)g * FOUT + tid] = o + fc_b[tid];
    }
}

// ---------------------------------------------------------------------------
extern "C" void kernel_launch(void* const* d_in, const int* in_sizes, int n_in,
                              void* d_out, int out_size, void* d_ws, size_t ws_size,
                              hipStream_t stream) {
    const float* x        = (const float*)d_in[0];
    const int*   ei       = (const int*)d_in[1];
    const int*   batch    = (const int*)d_in[2];
    const float* W1       = (const float*)d_in[3];
    const float* att_src1 = (const float*)d_in[4];
    const float* att_dst1 = (const float*)d_in[5];
    const float* b1       = (const float*)d_in[6];
    const float* W2       = (const float*)d_in[7];
    const float* att_src2 = (const float*)d_in[8];
    const float* att_dst2 = (const float*)d_in[9];
    const float* b2       = (const float*)d_in[10];
    const float* fc_w     = (const float*)d_in[11];
    const float* fc_b     = (const float*)d_in[12];
    float* out = (float*)d_out;

    // workspace carve-up (~55 MB)
    _Float16* h_pre  = (_Float16*)d_ws;                       // NN*D1 f16
    _Float16* h_act  = h_pre + (size_t)NN * D1;               // NN*D1 f16
    _Float16* w1t    = h_act + (size_t)NN * D1;               // 256*128
    _Float16* w2t    = w1t + 256 * FIN;                       // 256*256
    float* a_s       = (float*)(w2t + 256 * D1);              // [NN][4] node-major
    float* a_d       = a_s + (size_t)NN * 4;
    int*   cnt       = (int*)(a_d + (size_t)NN * 4);          // NN ints
    unsigned short* slot16 = (unsigned short*)(cnt + NN);     // NN*CAP u16 (9.6 MB)

    // ---- adjacency build (memset + single scatter; scan-free) ----
    hipMemsetAsync(cnt, 0, NN * sizeof(int), stream);
    k_scatter_direct<<<(EE / 2 + 255) / 256, 256, 0, stream>>>(ei, cnt, slot16);

    // ---- weight transposes (1 dispatch) ----
    k_cvt_w<<<(256 * (FIN + D1) + 255) / 256, 256, 0, stream>>>(W1, W2, w1t, w2t);

    dim3 ggrid((NN + BM - 1) / BM, D1 / BN);

    // ---- layer 1 (GEMM + fused logits, aggregate) ----
    k_gemm<FIN, float><<<ggrid, 256, 0, stream>>>(x, w1t, h_pre,
                                                  att_src1, att_dst1, a_s, a_d);
    k_aggregate<<<NN, 64, 0, stream>>>(h_pre, a_s, a_d, cnt, slot16, b1, h_act, 1);

    // ---- layer 2 ----
    k_gemm<D1, _Float16><<<ggrid, 256, 0, stream>>>(h_act, w2t, h_pre,
                                                    att_src2, att_dst2, a_s, a_d);
    k_aggregate<<<NN, 64, 0, stream>>>(h_pre, a_s, a_d, cnt, slot16, b2, h_act, 1);

    // ---- fused pool + fc ----
    k_pool_fc<<<NG, 256, 0, stream>>>(h_act, batch, fc_w, fc_b, out);
}

// Round 10
// 345.081 us; speedup vs baseline: 1.0584x; 1.0125x over previous
//
#include <hip/hip_runtime.h>
#include <cstddef>
#include <cstdint>

// Problem constants (fixed by the reference)
#define NN 50000      // nodes
#define EE 800000     // edges (before self loops)
#define FIN 128
#define D1 256        // HEADS*HID
#define HID 64
#define HEADS 4
#define NG 512
#define FOUT 64
#define NEG_SLOPE 0.2f
#define CAP 96        // slots per node; deg ~ Poisson(16), P(deg>96) ~ 1e-40

// Aggregate: R1-R6 channel-sliced arc refuted (L2 residency real but 8x
// metadata redundancy); R0/R7/R8 all pin at 3.73-3.77 TB/s fill rate ->
// fabric wall for the random-512B gather (h is L3-resident; FETCH = L2
// fills at ~466 GB/s/XCD). Aggregate is at its structural roofline.
// R9 tail cuts (int2 scatter, vectorized pool) landed -16 us. R10: last
// safe tail levers — memset folded into prep, int4 scatter, expm1f ->
// __expf-1 epilogue, pool MLP unroll.

typedef _Float16 f16x8 __attribute__((ext_vector_type(8)));
typedef _Float16 f16x4 __attribute__((ext_vector_type(4)));
typedef float f32x4 __attribute__((ext_vector_type(4)));

__device__ __forceinline__ float leaky(float x) { return x > 0.f ? x : NEG_SLOPE * x; }

// ---------------------------------------------------------------------------
// Prep: zero cnt + both weight transposes in ONE dispatch (replaces
// memset + cvt; removes one dispatch boundary from the critical path).
// Grid covers 256*(FIN+D1) = 98304 >= NN.
// ---------------------------------------------------------------------------
__global__ void k_prep(const float* __restrict__ W1, const float* __restrict__ W2,
                       _Float16* __restrict__ w1t, _Float16* __restrict__ w2t,
                       int* __restrict__ cnt) {
    int idx = blockIdx.x * 256 + threadIdx.x;
    if (idx < NN) cnt[idx] = 0;
    if (idx < 256 * FIN) {
        int n = idx / FIN, k = idx - n * FIN;
        w1t[idx] = (_Float16)W1[(size_t)k * 256 + n];
    } else if (idx < 256 * FIN + 256 * D1) {
        int j = idx - 256 * FIN;
        int n = j >> 8, k = j & 255;
        w2t[j] = (_Float16)W2[(size_t)k * 256 + n];
    }
}

// ---------------------------------------------------------------------------
// Adjacency build, scan-free: fixed-capacity slot array (CAP per node), u16.
// R10: 4 edges/thread, int4 loads (16 B/lane coalesced), quarter the waves.
// EE divisible by 4 -> no tail.
// ---------------------------------------------------------------------------
__global__ void k_scatter_direct(const int* __restrict__ ei, int* __restrict__ cnt,
                                 unsigned short* __restrict__ slot) {
    int i = (blockIdx.x * 256 + threadIdx.x) * 4;
    if (i < EE) {
        const int4 s4 = *(const int4*)(ei + i);
        const int4 d4 = *(const int4*)(ei + EE + i);
        int p;
        p = atomicAdd(&cnt[d4.x], 1);
        if (p < CAP) __builtin_nontemporal_store((unsigned short)s4.x,
                                                 &slot[(size_t)d4.x * CAP + p]);
        p = atomicAdd(&cnt[d4.y], 1);
        if (p < CAP) __builtin_nontemporal_store((unsigned short)s4.y,
                                                 &slot[(size_t)d4.y * CAP + p]);
        p = atomicAdd(&cnt[d4.z], 1);
        if (p < CAP) __builtin_nontemporal_store((unsigned short)s4.z,
                                                 &slot[(size_t)d4.z * CAP + p]);
        p = atomicAdd(&cnt[d4.w], 1);
        if (p < CAP) __builtin_nontemporal_store((unsigned short)s4.w,
                                                 &slot[(size_t)d4.w * CAP + p]);
    }
}

// ---------------------------------------------------------------------------
// MFMA fp16 GEMM (NT) with FUSED attention logits epilogue.
// C[M,256] = A[M,K] * Bt[256,K]^T, fp32 acc, fp16 out (row-major).
// BM=BN=128, BK=64; 4 waves 2x2; swapped-operand MFMA. Each wave's 64-ch
// slice == one head (head = 2*by + wn); a_s/a_d computed wave-locally.
// A is fp32 (layer 1, x) or fp16 (layer 2) via template.
// ---------------------------------------------------------------------------
#define BM 128
#define BN 128
#define BK 64
#define LDK (BK + 4)

template <int K, typename AT>
__global__ __launch_bounds__(256) void k_gemm(const AT* __restrict__ A,
                                              const _Float16* __restrict__ Bt,
                                              _Float16* __restrict__ C,
                                              const float* __restrict__ att_s,
                                              const float* __restrict__ att_d,
                                              float* __restrict__ a_s,
                                              float* __restrict__ a_d) {
    __shared__ _Float16 As[BM][LDK];
    __shared__ _Float16 Bs[BN][LDK];
    const int tid = threadIdx.x;
    const int lane = tid & 63;
    const int wave = tid >> 6;            // 0..3
    const int wm = wave & 1, wn = wave >> 1;
    const int m0 = blockIdx.x * BM;
    const int n0 = blockIdx.y * BN;
    const int row_m = lane & 15, quad = lane >> 4;

    f32x4 acc[4][4];
#pragma unroll
    for (int mi = 0; mi < 4; ++mi)
#pragma unroll
        for (int ni = 0; ni < 4; ++ni)
#pragma unroll
            for (int r = 0; r < 4; ++r) acc[mi][ni][r] = 0.f;

    const int c8 = (tid & 7) * 8;          // f16 column offset within row
    const int rr = tid >> 3;               // 0..31

    for (int k0 = 0; k0 < K; k0 += BK) {
#pragma unroll
        for (int p = 0; p < 4; ++p) {
            int r = p * 32 + rr;
            int gr = m0 + r; gr = gr < NN ? gr : NN - 1;
            f16x8 o;
            if constexpr (sizeof(AT) == 4) {
                const float4 v0 = *(const float4*)((const float*)A + (size_t)gr * K + k0 + c8);
                const float4 v1 = *(const float4*)((const float*)A + (size_t)gr * K + k0 + c8 + 4);
                o[0] = (_Float16)v0.x; o[1] = (_Float16)v0.y;
                o[2] = (_Float16)v0.z; o[3] = (_Float16)v0.w;
                o[4] = (_Float16)v1.x; o[5] = (_Float16)v1.y;
                o[6] = (_Float16)v1.z; o[7] = (_Float16)v1.w;
            } else {
                o = *(const f16x8*)((const _Float16*)A + (size_t)gr * K + k0 + c8);
            }
            *(f16x8*)(&As[r][c8]) = o;
        }
#pragma unroll
        for (int p = 0; p < 4; ++p) {
            int r = p * 32 + rr;
            f16x8 v = *(const f16x8*)(Bt + (size_t)(n0 + r) * K + k0 + c8);
            *(f16x8*)(&Bs[r][c8]) = v;
        }
        __syncthreads();
#pragma unroll
        for (int kc = 0; kc < BK; kc += 32) {
            f16x8 af[4], bf[4];
#pragma unroll
            for (int mi = 0; mi < 4; ++mi)
                af[mi] = *(const f16x8*)(&As[wm * 64 + mi * 16 + row_m][kc + quad * 8]);
#pragma unroll
            for (int ni = 0; ni < 4; ++ni)
                bf[ni] = *(const f16x8*)(&Bs[wn * 64 + ni * 16 + row_m][kc + quad * 8]);
            // swapped operands: D holds C^T fragment
#pragma unroll
            for (int mi = 0; mi < 4; ++mi)
#pragma unroll
                for (int ni = 0; ni < 4; ++ni)
                    acc[mi][ni] = __builtin_amdgcn_mfma_f32_16x16x32_f16(
                        bf[ni], af[mi], acc[mi][ni], 0, 0, 0);
        }
        __syncthreads();
    }
    // store C (row-major): value(lane, reg) of acc[mi][ni] =
    //   C[m0+wm*64+mi*16+row_m][n0+wn*64+ni*16+quad*4+reg]
#pragma unroll
    for (int mi = 0; mi < 4; ++mi) {
        int m = m0 + wm * 64 + mi * 16 + row_m;
        if (m < NN) {
#pragma unroll
            for (int ni = 0; ni < 4; ++ni) {
                f16x4 o;
                o[0] = (_Float16)acc[mi][ni][0];
                o[1] = (_Float16)acc[mi][ni][1];
                o[2] = (_Float16)acc[mi][ni][2];
                o[3] = (_Float16)acc[mi][ni][3];
                *(f16x4*)(C + (size_t)m * D1 + n0 + wn * 64 + ni * 16 + quad * 4) = o;
            }
        }
    }
    // fused logits: this wave's 64 channels == head (2*by + wn); local channel
    // of acc[mi][ni][r] is ni*16 + quad*4 + r.
    const int head = blockIdx.y * 2 + wn;
    const float* attsv = att_s + head * HID;
    const float* attdv = att_d + head * HID;
    float avs[4][4], avd[4][4];
#pragma unroll
    for (int ni = 0; ni < 4; ++ni)
#pragma unroll
        for (int r = 0; r < 4; ++r) {
            avs[ni][r] = attsv[ni * 16 + quad * 4 + r];
            avd[ni][r] = attdv[ni * 16 + quad * 4 + r];
        }
#pragma unroll
    for (int mi = 0; mi < 4; ++mi) {
        float ps = 0.f, pd = 0.f;
#pragma unroll
        for (int ni = 0; ni < 4; ++ni)
#pragma unroll
            for (int r = 0; r < 4; ++r) {
                ps += acc[mi][ni][r] * avs[ni][r];
                pd += acc[mi][ni][r] * avd[ni][r];
            }
        ps += __shfl_xor(ps, 16); ps += __shfl_xor(ps, 32);
        pd += __shfl_xor(pd, 16); pd += __shfl_xor(pd, 32);
        int m = m0 + wm * 64 + mi * 16 + row_m;
        if (quad == 0 && m < NN) {
            a_s[m * 4 + head] = ps;   // node-major [NN][4]
            a_d[m * 4 + head] = pd;
        }
    }
}

// ---------------------------------------------------------------------------
// GAT softmax + aggregation (R7-proven form, at its fabric roofline):
// one wave per dst node, 64-thr blocks. Self-loop folded in.
// Phase 1: lanes batch-compute exp weights into LDS. Phase 2: wave-uniform
// scalar loop — slot[j] uniform load, weight via LDS broadcast, f16x4 gather.
// R10: expm1f -> __expf-1 in the ELU epilogue (f16 out: err ~1e-7).
// ---------------------------------------------------------------------------
__global__ __launch_bounds__(64) void k_aggregate(
    const _Float16* __restrict__ h, const float* __restrict__ a_s,
    const float* __restrict__ a_d, const int* __restrict__ cnt,
    const unsigned short* __restrict__ slot, const float* __restrict__ bias,
    _Float16* __restrict__ out, int apply_elu) {
    const int n = blockIdx.x;
    const int tid = threadIdx.x;              // 0..63
    const int myhead = tid >> 4;
    const int c4 = tid * 4;
    const int start = n * CAP;
    const int deg = cnt[n];
    const int end = start + (deg < CAP ? deg : CAP);

    __shared__ float s_w[64][4];

    const float4 ad = *(const float4*)(a_d + (size_t)n * 4);

    // self-loop seed: w_self per head, acc = w_self * h[n]
    const float4 asn = *(const float4*)(a_s + (size_t)n * 4);
    float w0 = __expf(leaky(asn.x + ad.x));
    float w1 = __expf(leaky(asn.y + ad.y));
    float w2 = __expf(leaky(asn.z + ad.z));
    float w3 = __expf(leaky(asn.w + ad.w));
    const float wself = (myhead == 0) ? w0 : (myhead == 1) ? w1 : (myhead == 2) ? w2 : w3;
    const f16x4 hn = *(const f16x4*)(h + ((size_t)n << 8) + c4);
    float l = wself;
    float4 acc = make_float4(wself * (float)hn[0], wself * (float)hn[1],
                             wself * (float)hn[2], wself * (float)hn[3]);

    for (int base = start; base < end; base += 64) {
        const int len = min(64, end - base);
        if (tid < len) {
            const int s = (int)slot[base + tid];
            const float4 as = *(const float4*)(a_s + (size_t)s * 4);
            s_w[tid][0] = __expf(leaky(as.x + ad.x));
            s_w[tid][1] = __expf(leaky(as.y + ad.y));
            s_w[tid][2] = __expf(leaky(as.z + ad.z));
            s_w[tid][3] = __expf(leaky(as.w + ad.w));
        }
        __syncthreads();
#pragma unroll 4
        for (int jj = 0; jj < len; ++jj) {
            const int s = (int)slot[base + jj];         // wave-uniform
            const float w = s_w[jj][myhead];
            const f16x4 hv = *(const f16x4*)(h + ((size_t)s << 8) + c4);
            l += w;
            acc.x += w * (float)hv[0];
            acc.y += w * (float)hv[1];
            acc.z += w * (float)hv[2];
            acc.w += w * (float)hv[3];
        }
        __syncthreads();
    }
    const float inv = 1.f / l;
    const float4 bb = *(const float4*)(bias + c4);
    float vx = acc.x * inv + bb.x;
    float vy = acc.y * inv + bb.y;
    float vz = acc.z * inv + bb.z;
    float vw = acc.w * inv + bb.w;
    if (apply_elu) {
        // __expf-1 instead of expm1f (libm): f16 output, err ~1e-7
        vx = vx > 0.f ? vx : __expf(vx) - 1.f;
        vy = vy > 0.f ? vy : __expf(vy) - 1.f;
        vz = vz > 0.f ? vz : __expf(vz) - 1.f;
        vw = vw > 0.f ? vw : __expf(vw) - 1.f;
    }
    f16x4 o;
    o[0] = (_Float16)vx; o[1] = (_Float16)vy; o[2] = (_Float16)vz; o[3] = (_Float16)vw;
    *(f16x4*)(out + (size_t)n * D1 + c4) = o;
}

// ---------------------------------------------------------------------------
// Fused global mean pool + final FC: one 256-thr block per graph.
// 4-warp vectorized sum; R10: unroll 4 on the node loop (4 rows in flight
// per wave -> latency cover at 2-blocks/CU occupancy).
// ---------------------------------------------------------------------------
__global__ __launch_bounds__(256) void k_pool_fc(const _Float16* __restrict__ h,
                                                 const int* __restrict__ batch,
                                                 const float* __restrict__ fc_w,
                                                 const float* __restrict__ fc_b,
                                                 float* __restrict__ out) {
    __shared__ float srow[4][D1];
    __shared__ float row[D1];
    const int g = blockIdx.x, tid = threadIdx.x;
    const int w = tid >> 6, lane = tid & 63;
    const int c4 = lane * 4;

    int lo = 0, hi = NN;
    while (lo < hi) { int mid = (lo + hi) >> 1; if (batch[mid] < g) lo = mid + 1; else hi = mid; }
    int start = lo;
    hi = NN;
    while (lo < hi) { int mid = (lo + hi) >> 1; if (batch[mid] < g + 1) lo = mid + 1; else hi = mid; }
    int end = lo;

    float a0 = 0.f, a1 = 0.f, a2 = 0.f, a3 = 0.f;
#pragma unroll 4
    for (int n = start + w; n < end; n += 4) {
        const f16x4 v = *(const f16x4*)(h + (size_t)n * D1 + c4);
        a0 += (float)v[0]; a1 += (float)v[1];
        a2 += (float)v[2]; a3 += (float)v[3];
    }
    srow[w][c4 + 0] = a0; srow[w][c4 + 1] = a1;
    srow[w][c4 + 2] = a2; srow[w][c4 + 3] = a3;
    __syncthreads();
    const float inv = 1.f / fmaxf((float)(end - start), 1.f);
    row[tid] = (srow[0][tid] + srow[1][tid] + srow[2][tid] + srow[3][tid]) * inv;
    __syncthreads();
    if (tid < FOUT) {
        float o = 0.f;
#pragma unroll 4
        for (int k = 0; k < D1; ++k) o += row[k] * fc_w[k * FOUT + tid];
        out[(size_t)g * FOUT + tid] = o + fc_b[tid];
    }
}

// ---------------------------------------------------------------------------
extern "C" void kernel_launch(void* const* d_in, const int* in_sizes, int n_in,
                              void* d_out, int out_size, void* d_ws, size_t ws_size,
                              hipStream_t stream) {
    const float* x        = (const float*)d_in[0];
    const int*   ei       = (const int*)d_in[1];
    const int*   batch    = (const int*)d_in[2];
    const float* W1       = (const float*)d_in[3];
    const float* att_src1 = (const float*)d_in[4];
    const float* att_dst1 = (const float*)d_in[5];
    const float* b1       = (const float*)d_in[6];
    const float* W2       = (const float*)d_in[7];
    const float* att_src2 = (const float*)d_in[8];
    const float* att_dst2 = (const float*)d_in[9];
    const float* b2       = (const float*)d_in[10];
    const float* fc_w     = (const float*)d_in[11];
    const float* fc_b     = (const float*)d_in[12];
    float* out = (float*)d_out;

    // workspace carve-up (~55 MB)
    _Float16* h_pre  = (_Float16*)d_ws;                       // NN*D1 f16
    _Float16* h_act  = h_pre + (size_t)NN * D1;               // NN*D1 f16
    _Float16* w1t    = h_act + (size_t)NN * D1;               // 256*128
    _Float16* w2t    = w1t + 256 * FIN;                       // 256*256
    float* a_s       = (float*)(w2t + 256 * D1);              // [NN][4] node-major
    float* a_d       = a_s + (size_t)NN * 4;
    int*   cnt       = (int*)(a_d + (size_t)NN * 4);          // NN ints
    unsigned short* slot16 = (unsigned short*)(cnt + NN);     // NN*CAP u16 (9.6 MB)

    // ---- prep (cnt zero + weight transposes, 1 dispatch) ----
    k_prep<<<(256 * (FIN + D1) + 255) / 256, 256, 0, stream>>>(W1, W2, w1t, w2t, cnt);

    // ---- adjacency build (single scatter, 4 edges/thread) ----
    k_scatter_direct<<<(EE / 4 + 255) / 256, 256, 0, stream>>>(ei, cnt, slot16);

    dim3 ggrid((NN + BM - 1) / BM, D1 / BN);

    // ---- layer 1 (GEMM + fused logits, aggregate) ----
    k_gemm<FIN, float><<<ggrid, 256, 0, stream>>>(x, w1t, h_pre,
                                                  att_src1, att_dst1, a_s, a_d);
    k_aggregate<<<NN, 64, 0, stream>>>(h_pre, a_s, a_d, cnt, slot16, b1, h_act, 1);

    // ---- layer 2 ----
    k_gemm<D1, _Float16><<<ggrid, 256, 0, stream>>>(h_act, w2t, h_pre,
                                                    att_src2, att_dst2, a_s, a_d);
    k_aggregate<<<NN, 64, 0, stream>>>(h_pre, a_s, a_d, cnt, slot16, b2, h_act, 1);

    // ---- fused pool + fc ----
    k_pool_fc<<<NG, 256, 0, stream>>>(h_act, batch, fc_w, fc_b, out);
}